// Round 7
// baseline (456.115 us; speedup 1.0000x reference)
//
#include <hip/hip_runtime.h>
#include <hip/hip_bf16.h>

#define TT 1024
#define KS 64

typedef __attribute__((ext_vector_type(8))) short bf16x8;
typedef __attribute__((ext_vector_type(4))) float f32x4;

__device__ __forceinline__ unsigned short f2bf(float x) {
    union { __hip_bfloat16 h; unsigned short s; } u;
    u.h = __float2bfloat16(x);
    return u.s;
}
__device__ __forceinline__ float bflo(unsigned u) {
    union { unsigned v; float f; } w; w.v = u << 16; return w.f;
}
__device__ __forceinline__ float bfhi(unsigned u) {
    union { unsigned v; float f; } w; w.v = u & 0xFFFF0000u; return w.f;
}
// pack two f32 -> one dword of 2x bf16 (lo = a, hi = b)
__device__ __forceinline__ unsigned cvtpk(float a, float b) {
    unsigned r;
    asm("v_cvt_pk_bf16_f32 %0, %1, %2" : "=v"(r) : "v"(a), "v"(b));
    return r;
}
// packed 16-bit add (per-half, no cross carry) — exponent-field adjust
__device__ __forceinline__ unsigned pkadd(unsigned a, unsigned b) {
    unsigned r;
    asm("v_pk_add_u16 %0, %1, %2" : "=v"(r) : "v"(a), "v"(b));
    return r;
}

// ---------------------------------------------------------------------------
// Pre-pass: g = bf16(exp(emissions)), massively parallel, memory-bound.
// ---------------------------------------------------------------------------
__global__ __launch_bounds__(256) void crf_expem(
    const float* __restrict__ em, uint4* __restrict__ g, long long n8)
{
    long long i = (long long)blockIdx.x * blockDim.x + threadIdx.x;
    const long long stride = (long long)gridDim.x * blockDim.x;
    const float4* p = (const float4*)em;
    for (; i < n8; i += stride) {
        float4 a = p[i * 2], b = p[i * 2 + 1];
        uint4 o;
        o.x = (unsigned)f2bf(__expf(a.x)) | ((unsigned)f2bf(__expf(a.y)) << 16);
        o.y = (unsigned)f2bf(__expf(a.z)) | ((unsigned)f2bf(__expf(a.w)) << 16);
        o.z = (unsigned)f2bf(__expf(b.x)) | ((unsigned)f2bf(__expf(b.y)) << 16);
        o.w = (unsigned)f2bf(__expf(b.z)) | ((unsigned)f2bf(__expf(b.w)) << 16);
        g[i] = o;
    }
}

// ---------------------------------------------------------------------------
// Forward recursion via MFMA with LANE-LOCAL repack. One wave = 16 sequences.
// Compute W'^T = Etilde . W^T  (E as A-operand, W as B-operand):
//   sigma(m, rr) = 32*(m>>1) + 8*(rr>>2) + 4*(m&1) + (rr&3)
//   A (Etilde, const): lane(c,h) tile m, kk, reg e = E[32kk+8h+e][sigma(m,c)]
//   B (state W, bf16):  lane(c,h) kk, reg e        = W[seq c][32kk+8h+e]
//   D tile m (f32x4):   lane(c,h) reg r            = W'[seq c][sigma(m,4h+r)]
// sigma chosen so lane's 16 D-values == its 16 next-step B-frag values:
//   af_kk[e] = d_{2kk+(e>>2)}[e&3]   -> NO cross-lane exchange, NO LDS.
// Normalizer: r0 = W'[c][0] via one bpermute; scale by 2^shift applied as a
// packed u16 exponent add on the bf16 words; M -= shift*ln2 (exact bookkeep).
// raw_j/raw_0 in e^(+-0.2) (E entries e^(+-0.1)), g in e^(+-6) -> exponents
// stay deep inside bf16 range; no under/overflow.
// ---------------------------------------------------------------------------
template<bool PRE>
__global__ __launch_bounds__(64, 1) void crf_logZ_mfma(
    const float* __restrict__ em,
    const uint4* __restrict__ g4,        // bf16 exp(em), 8 values per uint4
    const int* __restrict__ mask,
    const float* __restrict__ trans,
    const float* __restrict__ startT,
    const float* __restrict__ endT,
    float* __restrict__ logZ)
{
    const int l = threadIdx.x;
    const int c = l & 15;
    const int h = l >> 4;
    const long long b = (long long)blockIdx.x * 16 + c;

    // constant transition fragments (A-operand), permuted columns sigma(m,c)
    const int sigc = 8 * (c >> 2) + (c & 3);
    bf16x8 E[4][2];
#pragma unroll
    for (int m = 0; m < 4; ++m) {
        const int col = 32 * (m >> 1) + 4 * (m & 1) + sigc;
#pragma unroll
        for (int kk = 0; kk < 2; ++kk) {
            union { unsigned short s[8]; bf16x8 v; } u;
#pragma unroll
            for (int e = 0; e < 8; ++e)
                u.s[e] = f2bf(__expf(trans[(32 * kk + 8 * h + e) * KS + col]));
            E[m][kk] = u.v;
        }
    }

    const long long embase = b * (long long)TT * KS;
    const long long g4base = embase / 8;
    const long long epbase = embase / 4;
    const int* mrow = mask + b * TT;
    const float4* ep = (const float4*)em;

    // ---- state init at t=0: aw words = bf16(exp(em0_j + start_j)) ----
    unsigned aw0, aw1, aw2, aw3, aw4, aw5, aw6, aw7;
    {
        const float* erow = em + embase;
        float w0[16];
#pragma unroll
        for (int kk = 0; kk < 2; ++kk)
#pragma unroll
            for (int e = 0; e < 8; ++e) {
                const int j = 32 * kk + 8 * h + e;
                w0[8 * kk + e] = __expf(erow[j] + startT[j]);
            }
        aw0 = cvtpk(w0[0], w0[1]);   aw1 = cvtpk(w0[2], w0[3]);
        aw2 = cvtpk(w0[4], w0[5]);   aw3 = cvtpk(w0[6], w0[7]);
        aw4 = cvtpk(w0[8], w0[9]);   aw5 = cvtpk(w0[10], w0[11]);
        aw6 = cvtpk(w0[12], w0[13]); aw7 = cvtpk(w0[14], w0[15]);
    }
    float M = 0.f;

    // ---- prefetch buffers, 3 deep (1023 = 3*341 exactly) ----
    uint4  gb[3][2];
    float4 eb[3][4];
    int    mb[3];
#pragma unroll
    for (int s = 0; s < 3; ++s) {
        const int t = 1 + s;
        if (PRE) {
            gb[s][0] = g4[g4base + (long long)t * 8 + h];
            gb[s][1] = g4[g4base + (long long)t * 8 + 4 + h];
        } else {
            eb[s][0] = ep[epbase + (long long)t * 16 + 2 * h];
            eb[s][1] = ep[epbase + (long long)t * 16 + 2 * h + 1];
            eb[s][2] = ep[epbase + (long long)t * 16 + 8 + 2 * h];
            eb[s][3] = ep[epbase + (long long)t * 16 + 8 + 2 * h + 1];
        }
        mb[s] = mrow[t];
    }

#define CRF_STEP(t, s) do {                                                    \
    union { unsigned u[4]; bf16x8 v; } A0, A1;                                 \
    A0.u[0] = aw0; A0.u[1] = aw1; A0.u[2] = aw2; A0.u[3] = aw3;                \
    A1.u[0] = aw4; A1.u[1] = aw5; A1.u[2] = aw6; A1.u[3] = aw7;                \
    const f32x4 z = {0.f, 0.f, 0.f, 0.f};                                      \
    f32x4 d0 = __builtin_amdgcn_mfma_f32_16x16x32_bf16(E[0][0], A0.v, z,0,0,0);\
    f32x4 d1 = __builtin_amdgcn_mfma_f32_16x16x32_bf16(E[1][0], A0.v, z,0,0,0);\
    f32x4 d2 = __builtin_amdgcn_mfma_f32_16x16x32_bf16(E[2][0], A0.v, z,0,0,0);\
    f32x4 d3 = __builtin_amdgcn_mfma_f32_16x16x32_bf16(E[3][0], A0.v, z,0,0,0);\
    d0 = __builtin_amdgcn_mfma_f32_16x16x32_bf16(E[0][1], A1.v, d0, 0,0,0);    \
    d1 = __builtin_amdgcn_mfma_f32_16x16x32_bf16(E[1][1], A1.v, d1, 0,0,0);    \
    d2 = __builtin_amdgcn_mfma_f32_16x16x32_bf16(E[2][1], A1.v, d2, 0,0,0);    \
    d3 = __builtin_amdgcn_mfma_f32_16x16x32_bf16(E[3][1], A1.v, d3, 0,0,0);    \
    const float r0 = __shfl(d0.x, c);    /* raw0 of seq c (lane (c,0)) */      \
    float g00,g01,g02,g03,g10,g11,g12,g13,g20,g21,g22,g23,g30,g31,g32,g33;     \
    if (PRE) {                                                                 \
        const uint4 v0 = gb[s][0], v1 = gb[s][1];                              \
        g00 = bflo(v0.x); g01 = bfhi(v0.x); g02 = bflo(v0.y); g03 = bfhi(v0.y);\
        g10 = bflo(v0.z); g11 = bfhi(v0.z); g12 = bflo(v0.w); g13 = bfhi(v0.w);\
        g20 = bflo(v1.x); g21 = bfhi(v1.x); g22 = bflo(v1.y); g23 = bfhi(v1.y);\
        g30 = bflo(v1.z); g31 = bfhi(v1.z); g32 = bflo(v1.w); g33 = bfhi(v1.w);\
    } else {                                                                   \
        g00 = __expf(eb[s][0].x); g01 = __expf(eb[s][0].y);                    \
        g02 = __expf(eb[s][0].z); g03 = __expf(eb[s][0].w);                    \
        g10 = __expf(eb[s][1].x); g11 = __expf(eb[s][1].y);                    \
        g12 = __expf(eb[s][1].z); g13 = __expf(eb[s][1].w);                    \
        g20 = __expf(eb[s][2].x); g21 = __expf(eb[s][2].y);                    \
        g22 = __expf(eb[s][2].z); g23 = __expf(eb[s][2].w);                    \
        g30 = __expf(eb[s][3].x); g31 = __expf(eb[s][3].y);                    \
        g32 = __expf(eb[s][3].z); g33 = __expf(eb[s][3].w);                    \
    }                                                                          \
    const int sh = 127 - (int)((__float_as_uint(r0) >> 23) & 0xff);            \
    const unsigned k16 = (unsigned)(unsigned short)(sh * 128);                  \
    const unsigned kadd = (k16 << 16) | k16;                                   \
    const unsigned q0 = pkadd(cvtpk(d0.x * g00, d0.y * g01), kadd);            \
    const unsigned q1 = pkadd(cvtpk(d0.z * g02, d0.w * g03), kadd);            \
    const unsigned q2 = pkadd(cvtpk(d1.x * g10, d1.y * g11), kadd);            \
    const unsigned q3 = pkadd(cvtpk(d1.z * g12, d1.w * g13), kadd);            \
    const unsigned q4 = pkadd(cvtpk(d2.x * g20, d2.y * g21), kadd);            \
    const unsigned q5 = pkadd(cvtpk(d2.z * g22, d2.w * g23), kadd);            \
    const unsigned q6 = pkadd(cvtpk(d3.x * g30, d3.y * g31), kadd);            \
    const unsigned q7 = pkadd(cvtpk(d3.z * g32, d3.w * g33), kadd);            \
    const int mv = mb[s];                                                      \
    if (__ballot(mv != 0) == ~0ULL) {                                          \
        aw0 = q0; aw1 = q1; aw2 = q2; aw3 = q3;                                \
        aw4 = q4; aw5 = q5; aw6 = q6; aw7 = q7;                                \
        M -= (float)sh * 0.693147180559945f;                                   \
    } else {                                                                   \
        aw0 = mv ? q0 : aw0; aw1 = mv ? q1 : aw1;                              \
        aw2 = mv ? q2 : aw2; aw3 = mv ? q3 : aw3;                              \
        aw4 = mv ? q4 : aw4; aw5 = mv ? q5 : aw5;                              \
        aw6 = mv ? q6 : aw6; aw7 = mv ? q7 : aw7;                              \
        M = mv ? (M - (float)sh * 0.693147180559945f) : M;                     \
    }                                                                          \
    if ((t) + 3 < TT) {                                                        \
        if (PRE) {                                                             \
            gb[s][0] = g4[g4base + (long long)((t) + 3) * 8 + h];              \
            gb[s][1] = g4[g4base + (long long)((t) + 3) * 8 + 4 + h];          \
        } else {                                                               \
            eb[s][0] = ep[epbase + (long long)((t) + 3) * 16 + 2 * h];         \
            eb[s][1] = ep[epbase + (long long)((t) + 3) * 16 + 2 * h + 1];     \
            eb[s][2] = ep[epbase + (long long)((t) + 3) * 16 + 8 + 2 * h];     \
            eb[s][3] = ep[epbase + (long long)((t) + 3) * 16 + 8 + 2 * h + 1]; \
        }                                                                      \
        mb[s] = mrow[(t) + 3];                                                 \
    }                                                                          \
} while (0)

    for (int t0 = 1; t0 < TT; t0 += 3) {
        CRF_STEP(t0    , 0);
        CRF_STEP(t0 + 1, 1);
        CRF_STEP(t0 + 2, 2);
    }
#undef CRF_STEP

    // logZ_b = M + log(sum_j w_j * exp(end_j))
    float val = 0.f;
    {
        const unsigned a[8] = {aw0, aw1, aw2, aw3, aw4, aw5, aw6, aw7};
#pragma unroll
        for (int kk = 0; kk < 2; ++kk)
#pragma unroll
            for (int wi = 0; wi < 4; ++wi) {
                const int j0 = 32 * kk + 8 * h + 2 * wi;
                const unsigned wq = a[4 * kk + wi];
                val += bflo(wq) * __expf(endT[j0]);
                val += bfhi(wq) * __expf(endT[j0 + 1]);
            }
    }
    val += __shfl_xor(val, 16);
    val += __shfl_xor(val, 32);
    if (l < 16) logZ[(long long)blockIdx.x * 16 + l] = M + __logf(val);
}

// ---------------------------------------------------------------------------
// Gold path score, one block (256 thr) per batch, strided over T.
// ---------------------------------------------------------------------------
__global__ __launch_bounds__(256) void crf_gold_kernel(
    const float* __restrict__ em, const int* __restrict__ tags,
    const int* __restrict__ mask, const float* __restrict__ trans,
    const float* __restrict__ startT, const float* __restrict__ endT,
    float* __restrict__ gold, int T)
{
    const int b = blockIdx.x;
    const int tid = threadIdx.x;
    const float* emb = em + (size_t)b * T * KS;
    const int* tb = tags + (size_t)b * T;
    const int* mb = mask + (size_t)b * T;

    float acc = 0.f;
    int cnt = 0;
    for (int t = tid; t < T; t += 256) {
        int tg = tb[t];
        int mv = mb[t];
        float mf = mv ? 1.f : 0.f;
        acc += emb[t * KS + tg] * mf;
        if (t >= 1) acc += trans[tb[t - 1] * KS + tg] * mf;
        cnt += mv ? 1 : 0;
    }
#pragma unroll
    for (int off = 32; off; off >>= 1) {
        acc += __shfl_xor(acc, off);
        cnt += __shfl_xor(cnt, off);
    }
    __shared__ float wacc[4];
    __shared__ int   wcnt[4];
    int wv = tid >> 6;
    if ((tid & 63) == 0) { wacc[wv] = acc; wcnt[wv] = cnt; }
    __syncthreads();
    if (tid == 0) {
        float a = wacc[0] + wacc[1] + wacc[2] + wacc[3];
        int   cc = wcnt[0] + wcnt[1] + wcnt[2] + wcnt[3];
        gold[b] = a + startT[tb[0]] + endT[tb[cc - 1]];
    }
}

// ---------------------------------------------------------------------------
// mean(logZ - gold) -> scalar
// ---------------------------------------------------------------------------
__global__ __launch_bounds__(512) void crf_reduce_kernel(
    const float* __restrict__ logZ, const float* __restrict__ gold,
    float* __restrict__ out, int B)
{
    int tid = threadIdx.x;
    float v = 0.f;
    for (int i = tid; i < B; i += 512) v += logZ[i] - gold[i];
#pragma unroll
    for (int off = 32; off; off >>= 1) v += __shfl_xor(v, off);
    __shared__ float ws[8];
    int w = tid >> 6;
    if ((tid & 63) == 0) ws[w] = v;
    __syncthreads();
    if (tid == 0) {
        float s = 0.f;
#pragma unroll
        for (int k = 0; k < 8; ++k) s += ws[k];
        out[0] = s / (float)B;
    }
}

// ---------------------------------------------------------------------------
extern "C" void kernel_launch(void* const* d_in, const int* in_sizes, int n_in,
                              void* d_out, int out_size, void* d_ws, size_t ws_size,
                              hipStream_t stream)
{
    const float* emissions = (const float*)d_in[0];
    const int*   tags      = (const int*)d_in[1];
    const int*   mask      = (const int*)d_in[2];
    const float* trans     = (const float*)d_in[3];
    const float* startT    = (const float*)d_in[4];
    const float* endT      = (const float*)d_in[5];

    const int T = TT;
    const int B = in_sizes[1] / T;

    float* logZ = (float*)d_ws;
    float* gold = logZ + B;

    const size_t gbytes = (size_t)B * T * KS * 2;
    const bool pre = (ws_size >= 4096 + gbytes) && (B % 16 == 0);

    if (pre) {
        uint4* g = (uint4*)((char*)d_ws + 4096);
        long long n8 = (long long)B * T * KS / 8;
        crf_expem<<<4096, 256, 0, stream>>>(emissions, g, n8);
        crf_logZ_mfma<true><<<B / 16, 64, 0, stream>>>(
            emissions, (const uint4*)g, mask, trans, startT, endT, logZ);
    } else {
        crf_logZ_mfma<false><<<B / 16, 64, 0, stream>>>(
            emissions, nullptr, mask, trans, startT, endT, logZ);
    }
    crf_gold_kernel<<<B, 256, 0, stream>>>(emissions, tags, mask, trans, startT, endT, gold, T);
    crf_reduce_kernel<<<1, 512, 0, stream>>>(logZ, gold, (float*)d_out, B);
}

// Round 8
// 314.143 us; speedup vs baseline: 1.4519x; 1.4519x over previous
//
#include <hip/hip_runtime.h>
#include <hip/hip_bf16.h>

#define TT 1024
#define KS 64
#define PFD 8   // prefetch depth == unroll; 1024 steps = 128 x 8 (step 1024 is a masked dummy)

typedef __attribute__((ext_vector_type(8))) short bf16x8;
typedef __attribute__((ext_vector_type(4))) float f32x4;

__device__ __forceinline__ unsigned short f2bf(float x) {
    union { __hip_bfloat16 h; unsigned short s; } u;
    u.h = __float2bfloat16(x);
    return u.s;
}
__device__ __forceinline__ float bflo(unsigned u) {
    union { unsigned v; float f; } w; w.v = u << 16; return w.f;
}
__device__ __forceinline__ float bfhi(unsigned u) {
    union { unsigned v; float f; } w; w.v = u & 0xFFFF0000u; return w.f;
}
__device__ __forceinline__ unsigned cvtpk(float a, float b) {
    unsigned r;
    asm("v_cvt_pk_bf16_f32 %0, %1, %2" : "=v"(r) : "v"(a), "v"(b));
    return r;
}
__device__ __forceinline__ unsigned pkadd(unsigned a, unsigned b) {
    unsigned r;
    asm("v_pk_add_u16 %0, %1, %2" : "=v"(r) : "v"(a), "v"(b));
    return r;
}

// ---------------------------------------------------------------------------
// Pre-pass: g = bf16(exp(emissions)), massively parallel, memory-bound.
// ---------------------------------------------------------------------------
__global__ __launch_bounds__(256) void crf_expem(
    const float* __restrict__ em, uint4* __restrict__ g, long long n8)
{
    long long i = (long long)blockIdx.x * blockDim.x + threadIdx.x;
    const long long stride = (long long)gridDim.x * blockDim.x;
    const float4* p = (const float4*)em;
    for (; i < n8; i += stride) {
        float4 a = p[i * 2], b = p[i * 2 + 1];
        uint4 o;
        o.x = (unsigned)f2bf(__expf(a.x)) | ((unsigned)f2bf(__expf(a.y)) << 16);
        o.y = (unsigned)f2bf(__expf(a.z)) | ((unsigned)f2bf(__expf(a.w)) << 16);
        o.z = (unsigned)f2bf(__expf(b.x)) | ((unsigned)f2bf(__expf(b.y)) << 16);
        o.w = (unsigned)f2bf(__expf(b.z)) | ((unsigned)f2bf(__expf(b.w)) << 16);
        g[i] = o;
    }
}

// ---------------------------------------------------------------------------
// Forward recursion via MFMA, lane-local repack (round-7 verified mapping),
// asm-volatile depth-8 prefetch (un-sinkable), counted vmcnt, and an
// off-chain absolute exponent-shift normalizer.
//   sigma(m, rr) = 32*(m>>1) + 8*(rr>>2) + 4*(m&1) + (rr&3)
//   A (E, const): lane(c,h) tile m, kk, e = exp(trans)[32kk+8h+e][sigma(m,c)]
//   B (state W):  lane(c,h) kk, e        = W[seq c][32kk+8h+e]
//   D tile m:     lane(c,h) reg r        = W'[seq c][sigma(m,4h+r)]
//   -> af_kk[e] = d_{2kk+(e>>2)}[e&3]: zero cross-lane repack.
// Normalizer: kadd/sln2 for step t+1 are derived from the MEASURED bf16
// exponent of step t's output (sample aw0/aw4, quad-max via 2 shfl_xor) —
// absolute measurement, no feedback; M += s*ln2 is exact bookkeeping.
// ---------------------------------------------------------------------------
__global__ __launch_bounds__(64, 1) void crf_logZ_mfma8(
    const float* __restrict__ em,
    const uint4* __restrict__ g4,
    const int* __restrict__ mask,
    const float* __restrict__ trans,
    const float* __restrict__ startT,
    const float* __restrict__ endT,
    float* __restrict__ logZ)
{
    const int l = threadIdx.x;
    const int c = l & 15;
    const int h = l >> 4;
    const long long b = (long long)blockIdx.x * 16 + c;

    // constant transition fragments (A-operand), permuted columns sigma(m,c)
    const int sigc = 8 * (c >> 2) + (c & 3);
    bf16x8 E[4][2];
#pragma unroll
    for (int m = 0; m < 4; ++m) {
        const int col = 32 * (m >> 1) + 4 * (m & 1) + sigc;
#pragma unroll
        for (int kk = 0; kk < 2; ++kk) {
            union { unsigned short s[8]; bf16x8 v; } u;
#pragma unroll
            for (int e = 0; e < 8; ++e)
                u.s[e] = f2bf(__expf(trans[(32 * kk + 8 * h + e) * KS + col]));
            E[m][kk] = u.v;
        }
    }

    const long long embase = b * (long long)TT * KS;
    const unsigned long long gp =
        (unsigned long long)(const void*)((const char*)g4 + embase * 2 + h * 16);
    const unsigned long long mp =
        (unsigned long long)(const void*)(mask + b * TT);

    // ---- state init at t=0: aw = bf16(exp(em0_j + start_j)) ----
    unsigned aw0, aw1, aw2, aw3, aw4, aw5, aw6, aw7;
    {
        const float* erow = em + embase;
        float w0[16];
#pragma unroll
        for (int kk = 0; kk < 2; ++kk)
#pragma unroll
            for (int e = 0; e < 8; ++e) {
                const int j = 32 * kk + 8 * h + e;
                w0[8 * kk + e] = __expf(erow[j] + startT[j]);
            }
        aw0 = cvtpk(w0[0], w0[1]);   aw1 = cvtpk(w0[2], w0[3]);
        aw2 = cvtpk(w0[4], w0[5]);   aw3 = cvtpk(w0[6], w0[7]);
        aw4 = cvtpk(w0[8], w0[9]);   aw5 = cvtpk(w0[10], w0[11]);
        aw6 = cvtpk(w0[12], w0[13]); aw7 = cvtpk(w0[14], w0[15]);
    }
    float M = 0.f;

    // ---- depth-8 prefetch slots (asm volatile -> cannot be sunk) ----
    uint4 ga[PFD], gc[PFD];
    int   mvp[PFD];
#pragma unroll
    for (int u = 0; u < PFD; ++u) {
        const unsigned long long a  = gp + (unsigned long long)(1 + u) * 128ull;
        const unsigned long long ma = mp + (unsigned long long)(1 + u) * 4ull;
        asm volatile("global_load_dwordx4 %0, %1, off" : "=&v"(ga[u]) : "v"(a));
        asm volatile("global_load_dwordx4 %0, %1, off offset:64" : "=&v"(gc[u]) : "v"(a));
        asm volatile("global_load_dword %0, %1, off" : "=&v"(mvp[u]) : "v"(ma));
    }

    // ---- controller state (normalizer for next step), from current aw ----
    unsigned kadd;
    float    sln2;
#define CRF_CTRL() do {                                                        \
    const unsigned l0 = aw0 & 0xffffu, h0 = aw0 >> 16;                         \
    const unsigned l4 = aw4 & 0xffffu, h4 = aw4 >> 16;                         \
    unsigned um = l0 > h0 ? l0 : h0;                                           \
    um = um > l4 ? um : l4;  um = um > h4 ? um : h4;                           \
    unsigned sx = (unsigned)__shfl_xor((int)um, 16); um = um > sx ? um : sx;   \
    sx = (unsigned)__shfl_xor((int)um, 32);          um = um > sx ? um : sx;   \
    const unsigned k16 = (0x3F80u - (um & 0x7F80u)) & 0xffffu;                 \
    kadd = (k16 << 16) | k16;                                                  \
    sln2 = (float)((int)((um >> 7) & 0xffu) - 127) * 0.693147180559945f;       \
} while (0)
    CRF_CTRL();

#define CRF_STEP(t, u) do {                                                    \
    union { unsigned uu[4]; bf16x8 v; } A0, A1;                                \
    A0.uu[0] = aw0; A0.uu[1] = aw1; A0.uu[2] = aw2; A0.uu[3] = aw3;            \
    A1.uu[0] = aw4; A1.uu[1] = aw5; A1.uu[2] = aw6; A1.uu[3] = aw7;            \
    const f32x4 z = {0.f, 0.f, 0.f, 0.f};                                      \
    f32x4 d0 = __builtin_amdgcn_mfma_f32_16x16x32_bf16(E[0][0], A0.v, z,0,0,0);\
    f32x4 d1 = __builtin_amdgcn_mfma_f32_16x16x32_bf16(E[1][0], A0.v, z,0,0,0);\
    f32x4 d2 = __builtin_amdgcn_mfma_f32_16x16x32_bf16(E[2][0], A0.v, z,0,0,0);\
    f32x4 d3 = __builtin_amdgcn_mfma_f32_16x16x32_bf16(E[3][0], A0.v, z,0,0,0);\
    d0 = __builtin_amdgcn_mfma_f32_16x16x32_bf16(E[0][1], A1.v, d0, 0,0,0);    \
    d1 = __builtin_amdgcn_mfma_f32_16x16x32_bf16(E[1][1], A1.v, d1, 0,0,0);    \
    d2 = __builtin_amdgcn_mfma_f32_16x16x32_bf16(E[2][1], A1.v, d2, 0,0,0);    \
    d3 = __builtin_amdgcn_mfma_f32_16x16x32_bf16(E[3][1], A1.v, d3, 0,0,0);    \
    asm volatile("s_waitcnt vmcnt(21)" ::: "memory");                          \
    __builtin_amdgcn_sched_barrier(0);                                         \
    const uint4 v0 = ga[u], v1 = gc[u];                                        \
    const int mvv = ((t) <= TT - 1) ? mvp[u] : 0;                              \
    const float g00 = bflo(v0.x), g01 = bfhi(v0.x);                            \
    const float g02 = bflo(v0.y), g03 = bfhi(v0.y);                            \
    const float g10 = bflo(v0.z), g11 = bfhi(v0.z);                            \
    const float g12 = bflo(v0.w), g13 = bfhi(v0.w);                            \
    const float g20 = bflo(v1.x), g21 = bfhi(v1.x);                            \
    const float g22 = bflo(v1.y), g23 = bfhi(v1.y);                            \
    const float g30 = bflo(v1.z), g31 = bfhi(v1.z);                            \
    const float g32 = bflo(v1.w), g33 = bfhi(v1.w);                            \
    const unsigned q0 = pkadd(cvtpk(d0.x * g00, d0.y * g01), kadd);            \
    const unsigned q1 = pkadd(cvtpk(d0.z * g02, d0.w * g03), kadd);            \
    const unsigned q2 = pkadd(cvtpk(d1.x * g10, d1.y * g11), kadd);            \
    const unsigned q3 = pkadd(cvtpk(d1.z * g12, d1.w * g13), kadd);            \
    const unsigned q4 = pkadd(cvtpk(d2.x * g20, d2.y * g21), kadd);            \
    const unsigned q5 = pkadd(cvtpk(d2.z * g22, d2.w * g23), kadd);            \
    const unsigned q6 = pkadd(cvtpk(d3.x * g30, d3.y * g31), kadd);            \
    const unsigned q7 = pkadd(cvtpk(d3.z * g32, d3.w * g33), kadd);            \
    aw0 = mvv ? q0 : aw0; aw1 = mvv ? q1 : aw1;                                \
    aw2 = mvv ? q2 : aw2; aw3 = mvv ? q3 : aw3;                                \
    aw4 = mvv ? q4 : aw4; aw5 = mvv ? q5 : aw5;                                \
    aw6 = mvv ? q6 : aw6; aw7 = mvv ? q7 : aw7;                                \
    M = mvv ? (M + sln2) : M;                                                  \
    {                                                                          \
        const int tn = ((t) + PFD <= TT - 1) ? ((t) + PFD) : (TT - 1);         \
        const unsigned long long a  = gp + (unsigned long long)tn * 128ull;    \
        const unsigned long long ma = mp + (unsigned long long)tn * 4ull;      \
        asm volatile("global_load_dwordx4 %0, %1, off" : "=&v"(ga[u]) : "v"(a)); \
        asm volatile("global_load_dwordx4 %0, %1, off offset:64" : "=&v"(gc[u]) : "v"(a)); \
        asm volatile("global_load_dword %0, %1, off" : "=&v"(mvp[u]) : "v"(ma)); \
    }                                                                          \
    CRF_CTRL();                                                                \
} while (0)

    for (int t0 = 1; t0 < TT + 1; t0 += PFD) {
        CRF_STEP(t0 + 0, 0);
        CRF_STEP(t0 + 1, 1);
        CRF_STEP(t0 + 2, 2);
        CRF_STEP(t0 + 3, 3);
        CRF_STEP(t0 + 4, 4);
        CRF_STEP(t0 + 5, 5);
        CRF_STEP(t0 + 6, 6);
        CRF_STEP(t0 + 7, 7);
    }
#undef CRF_STEP
#undef CRF_CTRL

    // logZ_b = M + log(sum_j w_j * exp(end_j))
    float val = 0.f;
    {
        const unsigned a[8] = {aw0, aw1, aw2, aw3, aw4, aw5, aw6, aw7};
#pragma unroll
        for (int kk = 0; kk < 2; ++kk)
#pragma unroll
            for (int wi = 0; wi < 4; ++wi) {
                const int j0 = 32 * kk + 8 * h + 2 * wi;
                const unsigned wq = a[4 * kk + wi];
                val += bflo(wq) * __expf(endT[j0]);
                val += bfhi(wq) * __expf(endT[j0 + 1]);
            }
    }
    val += __shfl_xor(val, 16);
    val += __shfl_xor(val, 32);
    if (l < 16) logZ[(long long)blockIdx.x * 16 + l] = M + __logf(val);
}

// ---------------------------------------------------------------------------
// Fallback (workspace too small): round-7 verified kernel, exp on the fly.
// ---------------------------------------------------------------------------
__global__ __launch_bounds__(64, 1) void crf_logZ_fb(
    const float* __restrict__ em, const int* __restrict__ mask,
    const float* __restrict__ trans, const float* __restrict__ startT,
    const float* __restrict__ endT, float* __restrict__ logZ)
{
    const int l = threadIdx.x;
    const int c = l & 15;
    const int h = l >> 4;
    const long long b = (long long)blockIdx.x * 16 + c;

    const int sigc = 8 * (c >> 2) + (c & 3);
    bf16x8 E[4][2];
#pragma unroll
    for (int m = 0; m < 4; ++m) {
        const int col = 32 * (m >> 1) + 4 * (m & 1) + sigc;
#pragma unroll
        for (int kk = 0; kk < 2; ++kk) {
            union { unsigned short s[8]; bf16x8 v; } u;
#pragma unroll
            for (int e = 0; e < 8; ++e)
                u.s[e] = f2bf(__expf(trans[(32 * kk + 8 * h + e) * KS + col]));
            E[m][kk] = u.v;
        }
    }
    const long long embase = b * (long long)TT * KS;
    const int* mrow = mask + b * TT;
    const float* erow = em + embase;

    unsigned aw[8];
    {
        float w0[16];
#pragma unroll
        for (int kk = 0; kk < 2; ++kk)
#pragma unroll
            for (int e = 0; e < 8; ++e) {
                const int j = 32 * kk + 8 * h + e;
                w0[8 * kk + e] = __expf(erow[j] + startT[j]);
            }
#pragma unroll
        for (int i = 0; i < 8; ++i) aw[i] = cvtpk(w0[2 * i], w0[2 * i + 1]);
    }
    float M = 0.f;

    for (int t = 1; t < TT; ++t) {
        union { unsigned uu[4]; bf16x8 v; } A0, A1;
#pragma unroll
        for (int i = 0; i < 4; ++i) { A0.uu[i] = aw[i]; A1.uu[i] = aw[4 + i]; }
        const f32x4 z = {0.f, 0.f, 0.f, 0.f};
        f32x4 d0 = __builtin_amdgcn_mfma_f32_16x16x32_bf16(E[0][0], A0.v, z,0,0,0);
        f32x4 d1 = __builtin_amdgcn_mfma_f32_16x16x32_bf16(E[1][0], A0.v, z,0,0,0);
        f32x4 d2 = __builtin_amdgcn_mfma_f32_16x16x32_bf16(E[2][0], A0.v, z,0,0,0);
        f32x4 d3 = __builtin_amdgcn_mfma_f32_16x16x32_bf16(E[3][0], A0.v, z,0,0,0);
        d0 = __builtin_amdgcn_mfma_f32_16x16x32_bf16(E[0][1], A1.v, d0, 0,0,0);
        d1 = __builtin_amdgcn_mfma_f32_16x16x32_bf16(E[1][1], A1.v, d1, 0,0,0);
        d2 = __builtin_amdgcn_mfma_f32_16x16x32_bf16(E[2][1], A1.v, d2, 0,0,0);
        d3 = __builtin_amdgcn_mfma_f32_16x16x32_bf16(E[3][1], A1.v, d3, 0,0,0);
        const float r0 = __shfl(d0.x, c);
        float gf[16];
#pragma unroll
        for (int kk = 0; kk < 2; ++kk)
#pragma unroll
            for (int e = 0; e < 8; ++e)
                gf[8 * kk + e] = __expf(erow[(long long)t * KS + 32 * kk + 8 * h + e]);
        const int sh = 127 - (int)((__float_as_uint(r0) >> 23) & 0xff);
        const unsigned k16 = (unsigned)(unsigned short)(sh * 128);
        const unsigned kadd = (k16 << 16) | k16;
        const int mv = mrow[t];
        const f32x4 dd[4] = {d0, d1, d2, d3};
#pragma unroll
        for (int i = 0; i < 8; ++i) {
            const f32x4 dv = dd[i >> 1];
            const float x = (i & 1) ? dv.z : dv.x;
            const float y = (i & 1) ? dv.w : dv.y;
            const unsigned q = pkadd(cvtpk(x * gf[2 * i], y * gf[2 * i + 1]), kadd);
            aw[i] = mv ? q : aw[i];
        }
        M = mv ? (M - (float)sh * 0.693147180559945f) : M;
    }

    float val = 0.f;
#pragma unroll
    for (int kk = 0; kk < 2; ++kk)
#pragma unroll
        for (int wi = 0; wi < 4; ++wi) {
            const int j0 = 32 * kk + 8 * h + 2 * wi;
            const unsigned wq = aw[4 * kk + wi];
            val += bflo(wq) * __expf(endT[j0]);
            val += bfhi(wq) * __expf(endT[j0 + 1]);
        }
    val += __shfl_xor(val, 16);
    val += __shfl_xor(val, 32);
    if (l < 16) logZ[(long long)blockIdx.x * 16 + l] = M + __logf(val);
}

// ---------------------------------------------------------------------------
// Gold path score, one block (256 thr) per batch, strided over T.
// ---------------------------------------------------------------------------
__global__ __launch_bounds__(256) void crf_gold_kernel(
    const float* __restrict__ em, const int* __restrict__ tags,
    const int* __restrict__ mask, const float* __restrict__ trans,
    const float* __restrict__ startT, const float* __restrict__ endT,
    float* __restrict__ gold, int T)
{
    const int b = blockIdx.x;
    const int tid = threadIdx.x;
    const float* emb = em + (size_t)b * T * KS;
    const int* tb = tags + (size_t)b * T;
    const int* mb = mask + (size_t)b * T;

    float acc = 0.f;
    int cnt = 0;
    for (int t = tid; t < T; t += 256) {
        int tg = tb[t];
        int mv = mb[t];
        float mf = mv ? 1.f : 0.f;
        acc += emb[t * KS + tg] * mf;
        if (t >= 1) acc += trans[tb[t - 1] * KS + tg] * mf;
        cnt += mv ? 1 : 0;
    }
#pragma unroll
    for (int off = 32; off; off >>= 1) {
        acc += __shfl_xor(acc, off);
        cnt += __shfl_xor(cnt, off);
    }
    __shared__ float wacc[4];
    __shared__ int   wcnt[4];
    int wv = tid >> 6;
    if ((tid & 63) == 0) { wacc[wv] = acc; wcnt[wv] = cnt; }
    __syncthreads();
    if (tid == 0) {
        float a = wacc[0] + wacc[1] + wacc[2] + wacc[3];
        int   cc = wcnt[0] + wcnt[1] + wcnt[2] + wcnt[3];
        gold[b] = a + startT[tb[0]] + endT[tb[cc - 1]];
    }
}

// ---------------------------------------------------------------------------
// mean(logZ - gold) -> scalar
// ---------------------------------------------------------------------------
__global__ __launch_bounds__(512) void crf_reduce_kernel(
    const float* __restrict__ logZ, const float* __restrict__ gold,
    float* __restrict__ out, int B)
{
    int tid = threadIdx.x;
    float v = 0.f;
    for (int i = tid; i < B; i += 512) v += logZ[i] - gold[i];
#pragma unroll
    for (int off = 32; off; off >>= 1) v += __shfl_xor(v, off);
    __shared__ float ws[8];
    int w = tid >> 6;
    if ((tid & 63) == 0) ws[w] = v;
    __syncthreads();
    if (tid == 0) {
        float s = 0.f;
#pragma unroll
        for (int k = 0; k < 8; ++k) s += ws[k];
        out[0] = s / (float)B;
    }
}

// ---------------------------------------------------------------------------
extern "C" void kernel_launch(void* const* d_in, const int* in_sizes, int n_in,
                              void* d_out, int out_size, void* d_ws, size_t ws_size,
                              hipStream_t stream)
{
    const float* emissions = (const float*)d_in[0];
    const int*   tags      = (const int*)d_in[1];
    const int*   mask      = (const int*)d_in[2];
    const float* trans     = (const float*)d_in[3];
    const float* startT    = (const float*)d_in[4];
    const float* endT      = (const float*)d_in[5];

    const int T = TT;
    const int B = in_sizes[1] / T;

    float* logZ = (float*)d_ws;
    float* gold = logZ + B;

    const size_t gbytes = (size_t)B * T * KS * 2;
    const bool pre = (ws_size >= 4096 + gbytes) && (B % 16 == 0);

    if (pre) {
        uint4* g = (uint4*)((char*)d_ws + 4096);
        long long n8 = (long long)B * T * KS / 8;
        crf_expem<<<2048, 256, 0, stream>>>(emissions, g, n8);
        crf_logZ_mfma8<<<B / 16, 64, 0, stream>>>(
            emissions, (const uint4*)g, mask, trans, startT, endT, logZ);
    } else {
        crf_logZ_fb<<<B / 16, 64, 0, stream>>>(
            emissions, mask, trans, startT, endT, logZ);
    }
    crf_gold_kernel<<<B, 256, 0, stream>>>(emissions, tags, mask, trans, startT, endT, gold, T);
    crf_reduce_kernel<<<1, 512, 0, stream>>>(logZ, gold, (float*)d_out, B);
}

// Round 11
// 262.264 us; speedup vs baseline: 1.7391x; 1.1978x over previous
//
#include <hip/hip_runtime.h>
#include <hip/hip_bf16.h>

#define TT 1024
#define KS 64
#define PFD 8   // prefetch depth == unroll; 1024 steps = 128 x 8 (t=1024 is a masked dummy)

typedef __attribute__((ext_vector_type(8))) short bf16x8;
typedef __attribute__((ext_vector_type(4))) float f32x4;

__device__ __forceinline__ unsigned short f2bf(float x) {
    union { __hip_bfloat16 h; unsigned short s; } u;
    u.h = __float2bfloat16(x);
    return u.s;
}
__device__ __forceinline__ float bflo(unsigned u) {
    union { unsigned v; float f; } w; w.v = u << 16; return w.f;
}
__device__ __forceinline__ float bfhi(unsigned u) {
    union { unsigned v; float f; } w; w.v = u & 0xFFFF0000u; return w.f;
}
__device__ __forceinline__ unsigned cvtpk(float a, float b) {
    unsigned r;
    asm("v_cvt_pk_bf16_f32 %0, %1, %2" : "=v"(r) : "v"(a), "v"(b));
    return r;
}
__device__ __forceinline__ unsigned pkadd(unsigned a, unsigned b) {
    unsigned r;
    asm("v_pk_add_u16 %0, %1, %2" : "=v"(r) : "v"(a), "v"(b));
    return r;
}

// ---------------------------------------------------------------------------
// Pre-pass: g = bf16(exp(emissions)), massively parallel, memory-bound.
// ---------------------------------------------------------------------------
__global__ __launch_bounds__(256) void crf_expem(
    const float* __restrict__ em, uint4* __restrict__ g, long long n8)
{
    long long i = (long long)blockIdx.x * blockDim.x + threadIdx.x;
    const long long stride = (long long)gridDim.x * blockDim.x;
    const float4* p = (const float4*)em;
    for (; i < n8; i += stride) {
        float4 a = p[i * 2], b = p[i * 2 + 1];
        uint4 o;
        o.x = (unsigned)f2bf(__expf(a.x)) | ((unsigned)f2bf(__expf(a.y)) << 16);
        o.y = (unsigned)f2bf(__expf(a.z)) | ((unsigned)f2bf(__expf(a.w)) << 16);
        o.z = (unsigned)f2bf(__expf(b.x)) | ((unsigned)f2bf(__expf(b.y)) << 16);
        o.w = (unsigned)f2bf(__expf(b.z)) | ((unsigned)f2bf(__expf(b.w)) << 16);
        g[i] = o;
    }
}

// ---------------------------------------------------------------------------
// Forward recursion via MFMA, lane-local repack (verified r7/r8 mapping):
//   sigma(m, rr) = 32*(m>>1) + 8*(rr>>2) + 4*(m&1) + (rr&3)
//   af_kk[e] = d_{2kk+(e>>2)}[e&3]  -> zero cross-lane repack.
// Round-8 proven skeleton: straight-line (NO branches while asm loads are in
// flight), depth-8 asm prefetch, vmcnt(21) waits, clamped tail refills,
// dummy masked step t=1024, per-step scalar mask loads.
// Controller fix vs r10: each measured correction is applied EXACTLY ONCE
// (deadbeat, eigenvalue 0). r10 applied the same correction 4x under a
// zero-order hold -> closed-loop eigenvalue -3 -> exponent divergence -> NaN.
// Schedule: measure after step0 -> apply only at step2; measure after step4
// -> apply only at step6. Non-apply steps use scale 1 (plain cvtpk, no M
// update). Level after each apply = 127 + 2-step drift; intra-window
// excursion <= ~45 bits, deep inside the 8-bit exponent budget. CTRL's two
// serial ds_swizzles get >=2 steps of slack -> latency hidden.
// ---------------------------------------------------------------------------
__global__ __launch_bounds__(64, 1) void crf_logZ_v11(
    const float* __restrict__ em,
    const uint4* __restrict__ g4,
    const int* __restrict__ mask,
    const float* __restrict__ trans,
    const float* __restrict__ startT,
    const float* __restrict__ endT,
    float* __restrict__ logZ)
{
    const int l = threadIdx.x;
    const int c = l & 15;
    const int h = l >> 4;
    const long long b = (long long)blockIdx.x * 16 + c;

    // constant transition fragments (A-operand), permuted columns sigma(m,c)
    const int sigc = 8 * (c >> 2) + (c & 3);
    bf16x8 E[4][2];
#pragma unroll
    for (int m = 0; m < 4; ++m) {
        const int col = 32 * (m >> 1) + 4 * (m & 1) + sigc;
#pragma unroll
        for (int kk = 0; kk < 2; ++kk) {
            union { unsigned short s[8]; bf16x8 v; } u;
#pragma unroll
            for (int e = 0; e < 8; ++e)
                u.s[e] = f2bf(__expf(trans[(32 * kk + 8 * h + e) * KS + col]));
            E[m][kk] = u.v;
        }
    }

    const long long embase = b * (long long)TT * KS;
    const unsigned long long gp =
        (unsigned long long)(const void*)((const char*)g4 + embase * 2 + h * 16);
    const unsigned long long mp =
        (unsigned long long)(const void*)(mask + b * TT);

    // ---- state init at t=0: aw = bf16(exp(em0_j + start_j)) ----
    unsigned aw0, aw1, aw2, aw3, aw4, aw5, aw6, aw7;
    {
        const float* erow = em + embase;
        float w0[16];
#pragma unroll
        for (int kk = 0; kk < 2; ++kk)
#pragma unroll
            for (int e = 0; e < 8; ++e) {
                const int j = 32 * kk + 8 * h + e;
                w0[8 * kk + e] = __expf(erow[j] + startT[j]);
            }
        aw0 = cvtpk(w0[0], w0[1]);   aw1 = cvtpk(w0[2], w0[3]);
        aw2 = cvtpk(w0[4], w0[5]);   aw3 = cvtpk(w0[6], w0[7]);
        aw4 = cvtpk(w0[8], w0[9]);   aw5 = cvtpk(w0[10], w0[11]);
        aw6 = cvtpk(w0[12], w0[13]); aw7 = cvtpk(w0[14], w0[15]);
    }
    float M = 0.f;

    // ---- depth-8 prefetch slots (asm volatile -> cannot be sunk) ----
    uint4 ga[PFD], gc[PFD];
    int   mvp[PFD];
#pragma unroll
    for (int u = 0; u < PFD; ++u) {
        const unsigned long long a  = gp + (unsigned long long)(1 + u) * 128ull;
        const unsigned long long ma = mp + (unsigned long long)(1 + u) * 4ull;
        asm volatile("global_load_dwordx4 %0, %1, off" : "=&v"(ga[u]) : "v"(a));
        asm volatile("global_load_dwordx4 %0, %1, off offset:64" : "=&v"(gc[u]) : "v"(a));
        asm volatile("global_load_dword %0, %1, off" : "=&v"(mvp[u]) : "v"(ma));
    }

    // ---- controller state: measured normalizer, applied exactly once ----
    unsigned kadd = 0;
    float    sln2 = 0.f;
#define CRF_CTRL() do {                                                        \
    const unsigned l0 = aw0 & 0xffffu, h0 = aw0 >> 16;                         \
    const unsigned l4 = aw4 & 0xffffu, h4 = aw4 >> 16;                         \
    unsigned um = l0 > h0 ? l0 : h0;                                           \
    um = um > l4 ? um : l4;  um = um > h4 ? um : h4;                           \
    unsigned sx = (unsigned)__shfl_xor((int)um, 16); um = um > sx ? um : sx;   \
    sx = (unsigned)__shfl_xor((int)um, 32);          um = um > sx ? um : sx;   \
    const unsigned k16 = (0x3F80u - (um & 0x7F80u)) & 0xffffu;                 \
    kadd = (k16 << 16) | k16;                                                  \
    sln2 = (float)((int)((um >> 7) & 0xffu) - 127) * 0.693147180559945f;       \
} while (0)

#define CRF_STEP(t, u, APPLY) do {                                             \
    union { unsigned uu[4]; bf16x8 v; } A0, A1;                                \
    A0.uu[0] = aw0; A0.uu[1] = aw1; A0.uu[2] = aw2; A0.uu[3] = aw3;            \
    A1.uu[0] = aw4; A1.uu[1] = aw5; A1.uu[2] = aw6; A1.uu[3] = aw7;            \
    const f32x4 z = {0.f, 0.f, 0.f, 0.f};                                      \
    f32x4 d0 = __builtin_amdgcn_mfma_f32_16x16x32_bf16(E[0][0], A0.v, z,0,0,0);\
    f32x4 d1 = __builtin_amdgcn_mfma_f32_16x16x32_bf16(E[1][0], A0.v, z,0,0,0);\
    f32x4 d2 = __builtin_amdgcn_mfma_f32_16x16x32_bf16(E[2][0], A0.v, z,0,0,0);\
    f32x4 d3 = __builtin_amdgcn_mfma_f32_16x16x32_bf16(E[3][0], A0.v, z,0,0,0);\
    d0 = __builtin_amdgcn_mfma_f32_16x16x32_bf16(E[0][1], A1.v, d0, 0,0,0);    \
    d1 = __builtin_amdgcn_mfma_f32_16x16x32_bf16(E[1][1], A1.v, d1, 0,0,0);    \
    d2 = __builtin_amdgcn_mfma_f32_16x16x32_bf16(E[2][1], A1.v, d2, 0,0,0);    \
    d3 = __builtin_amdgcn_mfma_f32_16x16x32_bf16(E[3][1], A1.v, d3, 0,0,0);    \
    asm volatile("s_waitcnt vmcnt(21)" ::: "memory");                          \
    __builtin_amdgcn_sched_barrier(0);                                         \
    const uint4 v0 = ga[u], v1 = gc[u];                                        \
    const int mvv = ((t) <= TT - 1) ? mvp[u] : 0;                              \
    const float g00 = bflo(v0.x), g01 = bfhi(v0.x);                            \
    const float g02 = bflo(v0.y), g03 = bfhi(v0.y);                            \
    const float g10 = bflo(v0.z), g11 = bfhi(v0.z);                            \
    const float g12 = bflo(v0.w), g13 = bfhi(v0.w);                            \
    const float g20 = bflo(v1.x), g21 = bfhi(v1.x);                            \
    const float g22 = bflo(v1.y), g23 = bfhi(v1.y);                            \
    const float g30 = bflo(v1.z), g31 = bfhi(v1.z);                            \
    const float g32 = bflo(v1.w), g33 = bfhi(v1.w);                            \
    unsigned q0, q1, q2, q3, q4, q5, q6, q7;                                   \
    if (APPLY) {                                                               \
        q0 = pkadd(cvtpk(d0.x * g00, d0.y * g01), kadd);                       \
        q1 = pkadd(cvtpk(d0.z * g02, d0.w * g03), kadd);                       \
        q2 = pkadd(cvtpk(d1.x * g10, d1.y * g11), kadd);                       \
        q3 = pkadd(cvtpk(d1.z * g12, d1.w * g13), kadd);                       \
        q4 = pkadd(cvtpk(d2.x * g20, d2.y * g21), kadd);                       \
        q5 = pkadd(cvtpk(d2.z * g22, d2.w * g23), kadd);                       \
        q6 = pkadd(cvtpk(d3.x * g30, d3.y * g31), kadd);                       \
        q7 = pkadd(cvtpk(d3.z * g32, d3.w * g33), kadd);                       \
    } else {                                                                   \
        q0 = cvtpk(d0.x * g00, d0.y * g01);                                    \
        q1 = cvtpk(d0.z * g02, d0.w * g03);                                    \
        q2 = cvtpk(d1.x * g10, d1.y * g11);                                    \
        q3 = cvtpk(d1.z * g12, d1.w * g13);                                    \
        q4 = cvtpk(d2.x * g20, d2.y * g21);                                    \
        q5 = cvtpk(d2.z * g22, d2.w * g23);                                    \
        q6 = cvtpk(d3.x * g30, d3.y * g31);                                    \
        q7 = cvtpk(d3.z * g32, d3.w * g33);                                    \
    }                                                                          \
    aw0 = mvv ? q0 : aw0; aw1 = mvv ? q1 : aw1;                                \
    aw2 = mvv ? q2 : aw2; aw3 = mvv ? q3 : aw3;                                \
    aw4 = mvv ? q4 : aw4; aw5 = mvv ? q5 : aw5;                                \
    aw6 = mvv ? q6 : aw6; aw7 = mvv ? q7 : aw7;                                \
    if (APPLY) { M = mvv ? (M + sln2) : M; }                                   \
    {                                                                          \
        const int tn = ((t) + PFD <= TT - 1) ? ((t) + PFD) : (TT - 1);         \
        const unsigned long long a  = gp + (unsigned long long)tn * 128ull;    \
        const unsigned long long ma = mp + (unsigned long long)tn * 4ull;      \
        asm volatile("global_load_dwordx4 %0, %1, off" : "=&v"(ga[u]) : "v"(a)); \
        asm volatile("global_load_dwordx4 %0, %1, off offset:64" : "=&v"(gc[u]) : "v"(a)); \
        asm volatile("global_load_dword %0, %1, off" : "=&v"(mvp[u]) : "v"(ma)); \
    }                                                                          \
} while (0)

    // measure after steps 0 and 4; apply (exactly once each) at steps 2 and 6
    for (int t0 = 1; t0 < TT + 1; t0 += PFD) {
        CRF_STEP(t0 + 0, 0, 0);
        CRF_CTRL();
        CRF_STEP(t0 + 1, 1, 0);
        CRF_STEP(t0 + 2, 2, 1);
        CRF_STEP(t0 + 3, 3, 0);
        CRF_STEP(t0 + 4, 4, 0);
        CRF_CTRL();
        CRF_STEP(t0 + 5, 5, 0);
        CRF_STEP(t0 + 6, 6, 1);
        CRF_STEP(t0 + 7, 7, 0);
    }
#undef CRF_STEP
#undef CRF_CTRL

    // logZ_b = M + log(sum_j w_j * exp(end_j))
    float val = 0.f;
    {
        const unsigned a[8] = {aw0, aw1, aw2, aw3, aw4, aw5, aw6, aw7};
#pragma unroll
        for (int kk = 0; kk < 2; ++kk)
#pragma unroll
            for (int wi = 0; wi < 4; ++wi) {
                const int j0 = 32 * kk + 8 * h + 2 * wi;
                const unsigned wq = a[4 * kk + wi];
                val += bflo(wq) * __expf(endT[j0]);
                val += bfhi(wq) * __expf(endT[j0 + 1]);
            }
    }
    val += __shfl_xor(val, 16);
    val += __shfl_xor(val, 32);
    if (l < 16) logZ[(long long)blockIdx.x * 16 + l] = M + __logf(val);
}

// ---------------------------------------------------------------------------
// Fallback (workspace too small): round-7 verified kernel, exp on the fly.
// ---------------------------------------------------------------------------
__global__ __launch_bounds__(64, 1) void crf_logZ_fb(
    const float* __restrict__ em, const int* __restrict__ mask,
    const float* __restrict__ trans, const float* __restrict__ startT,
    const float* __restrict__ endT, float* __restrict__ logZ)
{
    const int l = threadIdx.x;
    const int c = l & 15;
    const int h = l >> 4;
    const long long b = (long long)blockIdx.x * 16 + c;

    const int sigc = 8 * (c >> 2) + (c & 3);
    bf16x8 E[4][2];
#pragma unroll
    for (int m = 0; m < 4; ++m) {
        const int col = 32 * (m >> 1) + 4 * (m & 1) + sigc;
#pragma unroll
        for (int kk = 0; kk < 2; ++kk) {
            union { unsigned short s[8]; bf16x8 v; } u;
#pragma unroll
            for (int e = 0; e < 8; ++e)
                u.s[e] = f2bf(__expf(trans[(32 * kk + 8 * h + e) * KS + col]));
            E[m][kk] = u.v;
        }
    }
    const long long embase = b * (long long)TT * KS;
    const int* mrow = mask + b * TT;
    const float* erow = em + embase;

    unsigned aw[8];
    {
        float w0[16];
#pragma unroll
        for (int kk = 0; kk < 2; ++kk)
#pragma unroll
            for (int e = 0; e < 8; ++e) {
                const int j = 32 * kk + 8 * h + e;
                w0[8 * kk + e] = __expf(erow[j] + startT[j]);
            }
#pragma unroll
        for (int i = 0; i < 8; ++i) aw[i] = cvtpk(w0[2 * i], w0[2 * i + 1]);
    }
    float M = 0.f;

    for (int t = 1; t < TT; ++t) {
        union { unsigned uu[4]; bf16x8 v; } A0, A1;
#pragma unroll
        for (int i = 0; i < 4; ++i) { A0.uu[i] = aw[i]; A1.uu[i] = aw[4 + i]; }
        const f32x4 z = {0.f, 0.f, 0.f, 0.f};
        f32x4 d0 = __builtin_amdgcn_mfma_f32_16x16x32_bf16(E[0][0], A0.v, z,0,0,0);
        f32x4 d1 = __builtin_amdgcn_mfma_f32_16x16x32_bf16(E[1][0], A0.v, z,0,0,0);
        f32x4 d2 = __builtin_amdgcn_mfma_f32_16x16x32_bf16(E[2][0], A0.v, z,0,0,0);
        f32x4 d3 = __builtin_amdgcn_mfma_f32_16x16x32_bf16(E[3][0], A0.v, z,0,0,0);
        d0 = __builtin_amdgcn_mfma_f32_16x16x32_bf16(E[0][1], A1.v, d0, 0,0,0);
        d1 = __builtin_amdgcn_mfma_f32_16x16x32_bf16(E[1][1], A1.v, d1, 0,0,0);
        d2 = __builtin_amdgcn_mfma_f32_16x16x32_bf16(E[2][1], A1.v, d2, 0,0,0);
        d3 = __builtin_amdgcn_mfma_f32_16x16x32_bf16(E[3][1], A1.v, d3, 0,0,0);
        const float r0 = __shfl(d0.x, c);
        float gf[16];
#pragma unroll
        for (int kk = 0; kk < 2; ++kk)
#pragma unroll
            for (int e = 0; e < 8; ++e)
                gf[8 * kk + e] = __expf(erow[(long long)t * KS + 32 * kk + 8 * h + e]);
        const int sh = 127 - (int)((__float_as_uint(r0) >> 23) & 0xff);
        const unsigned k16 = (unsigned)(unsigned short)(sh * 128);
        const unsigned kadd = (k16 << 16) | k16;
        const int mv = mrow[t];
        const f32x4 dd[4] = {d0, d1, d2, d3};
#pragma unroll
        for (int i = 0; i < 8; ++i) {
            const f32x4 dv = dd[i >> 1];
            const float x = (i & 1) ? dv.z : dv.x;
            const float y = (i & 1) ? dv.w : dv.y;
            const unsigned q = pkadd(cvtpk(x * gf[2 * i], y * gf[2 * i + 1]), kadd);
            aw[i] = mv ? q : aw[i];
        }
        M = mv ? (M - (float)sh * 0.693147180559945f) : M;
    }

    float val = 0.f;
#pragma unroll
    for (int kk = 0; kk < 2; ++kk)
#pragma unroll
        for (int wi = 0; wi < 4; ++wi) {
            const int j0 = 32 * kk + 8 * h + 2 * wi;
            const unsigned wq = aw[4 * kk + wi];
            val += bflo(wq) * __expf(endT[j0]);
            val += bfhi(wq) * __expf(endT[j0 + 1]);
        }
    val += __shfl_xor(val, 16);
    val += __shfl_xor(val, 32);
    if (l < 16) logZ[(long long)blockIdx.x * 16 + l] = M + __logf(val);
}

// ---------------------------------------------------------------------------
// Gold path score, one block (256 thr) per batch, strided over T.
// ---------------------------------------------------------------------------
__global__ __launch_bounds__(256) void crf_gold_kernel(
    const float* __restrict__ em, const int* __restrict__ tags,
    const int* __restrict__ mask, const float* __restrict__ trans,
    const float* __restrict__ startT, const float* __restrict__ endT,
    float* __restrict__ gold, int T)
{
    const int b = blockIdx.x;
    const int tid = threadIdx.x;
    const float* emb = em + (size_t)b * T * KS;
    const int* tb = tags + (size_t)b * T;
    const int* mb = mask + (size_t)b * T;

    float acc = 0.f;
    int cnt = 0;
    for (int t = tid; t < T; t += 256) {
        int tg = tb[t];
        int mv = mb[t];
        float mf = mv ? 1.f : 0.f;
        acc += emb[t * KS + tg] * mf;
        if (t >= 1) acc += trans[tb[t - 1] * KS + tg] * mf;
        cnt += mv ? 1 : 0;
    }
#pragma unroll
    for (int off = 32; off; off >>= 1) {
        acc += __shfl_xor(acc, off);
        cnt += __shfl_xor(cnt, off);
    }
    __shared__ float wacc[4];
    __shared__ int   wcnt[4];
    int wv = tid >> 6;
    if ((tid & 63) == 0) { wacc[wv] = acc; wcnt[wv] = cnt; }
    __syncthreads();
    if (tid == 0) {
        float a = wacc[0] + wacc[1] + wacc[2] + wacc[3];
        int   cc = wcnt[0] + wcnt[1] + wcnt[2] + wcnt[3];
        gold[b] = a + startT[tb[0]] + endT[tb[cc - 1]];
    }
}

// ---------------------------------------------------------------------------
// mean(logZ - gold) -> scalar
// ---------------------------------------------------------------------------
__global__ __launch_bounds__(512) void crf_reduce_kernel(
    const float* __restrict__ logZ, const float* __restrict__ gold,
    float* __restrict__ out, int B)
{
    int tid = threadIdx.x;
    float v = 0.f;
    for (int i = tid; i < B; i += 512) v += logZ[i] - gold[i];
#pragma unroll
    for (int off = 32; off; off >>= 1) v += __shfl_xor(v, off);
    __shared__ float ws[8];
    int w = tid >> 6;
    if ((tid & 63) == 0) ws[w] = v;
    __syncthreads();
    if (tid == 0) {
        float s = 0.f;
#pragma unroll
        for (int k = 0; k < 8; ++k) s += ws[k];
        out[0] = s / (float)B;
    }
}

// ---------------------------------------------------------------------------
extern "C" void kernel_launch(void* const* d_in, const int* in_sizes, int n_in,
                              void* d_out, int out_size, void* d_ws, size_t ws_size,
                              hipStream_t stream)
{
    const float* emissions = (const float*)d_in[0];
    const int*   tags      = (const int*)d_in[1];
    const int*   mask      = (const int*)d_in[2];
    const float* trans     = (const float*)d_in[3];
    const float* startT    = (const float*)d_in[4];
    const float* endT      = (const float*)d_in[5];

    const int T = TT;
    const int B = in_sizes[1] / T;

    float* logZ = (float*)d_ws;
    float* gold = logZ + B;

    const size_t gbytes = (size_t)B * T * KS * 2;
    const bool pre = (ws_size >= 4096 + gbytes) && (B % 16 == 0);

    if (pre) {
        uint4* g = (uint4*)((char*)d_ws + 4096);
        long long n8 = (long long)B * T * KS / 8;
        crf_expem<<<2048, 256, 0, stream>>>(emissions, g, n8);
        crf_logZ_v11<<<B / 16, 64, 0, stream>>>(
            emissions, (const uint4*)g, mask, trans, startT, endT, logZ);
    } else {
        crf_logZ_fb<<<B / 16, 64, 0, stream>>>(
            emissions, mask, trans, startT, endT, logZ);
    }
    crf_gold_kernel<<<B, 256, 0, stream>>>(emissions, tags, mask, trans, startT, endT, gold, T);
    crf_reduce_kernel<<<1, 512, 0, stream>>>(logZ, gold, (float*)d_out, B);
}

// Round 13
// 241.576 us; speedup vs baseline: 1.8881x; 1.0856x over previous
//
#include <hip/hip_runtime.h>
#include <hip/hip_bf16.h>

#define TT 1024
#define KS 64
#define PFD 4   // prefetch depth; t = 1..1024 (t=1024 is a masked dummy), 256 groups of 4

typedef __attribute__((ext_vector_type(8))) short bf16x8;
typedef __attribute__((ext_vector_type(4))) float f32x4;
typedef __attribute__((ext_vector_type(2))) float f32x2;

__device__ __forceinline__ unsigned short f2bf(float x) {
    union { __hip_bfloat16 h; unsigned short s; } u;
    u.h = __float2bfloat16(x);
    return u.s;
}
__device__ __forceinline__ float bflo(unsigned u) {
    union { unsigned v; float f; } w; w.v = u << 16; return w.f;
}
__device__ __forceinline__ float bfhi(unsigned u) {
    union { unsigned v; float f; } w; w.v = u & 0xFFFF0000u; return w.f;
}
__device__ __forceinline__ unsigned cvtpk(float a, float b) {
    unsigned r;
    asm("v_cvt_pk_bf16_f32 %0, %1, %2" : "=v"(r) : "v"(a), "v"(b));
    return r;
}
__device__ __forceinline__ unsigned pkadd(unsigned a, unsigned b) {
    unsigned r;
    asm("v_pk_add_u16 %0, %1, %2" : "=v"(r) : "v"(a), "v"(b));
    return r;
}
__device__ __forceinline__ f32x2 pkmul(f32x2 a, f32x2 b) {
    f32x2 r;
    asm("v_pk_mul_f32 %0, %1, %2" : "=v"(r) : "v"(a), "v"(b));
    return r;
}
__device__ __forceinline__ f32x2 lo2(f32x4 v) { return __builtin_shufflevector(v, v, 0, 1); }
__device__ __forceinline__ f32x2 hi2(f32x4 v) { return __builtin_shufflevector(v, v, 2, 3); }

// ---------------------------------------------------------------------------
// Pre-pass: g = f32 exp(emissions), memory-bound streaming.
// ---------------------------------------------------------------------------
__global__ __launch_bounds__(256) void crf_expem_f32(
    const float* __restrict__ em, float4* __restrict__ g, long long n4)
{
    long long i = (long long)blockIdx.x * blockDim.x + threadIdx.x;
    const long long stride = (long long)gridDim.x * blockDim.x;
    const float4* p = (const float4*)em;
    for (; i < n4; i += stride) {
        float4 a = p[i];
        float4 o;
        o.x = __expf(a.x); o.y = __expf(a.y);
        o.z = __expf(a.z); o.w = __expf(a.w);
        g[i] = o;
    }
}

// ---------------------------------------------------------------------------
// Fused kernel: blocks [0, nZ) run the logZ forward recursion (wave 0 only);
// blocks [nZ, nZ+B) compute the gold path score. The 512 gold blocks execute
// on the otherwise-idle CUs while the 32 serial logZ waves crunch.
//
// logZ: MFMA forward recursion, lane-local repack (verified r7/r8/r11):
//   sigma(m, rr) = 32*(m>>1) + 8*(rr>>2) + 4*(m&1) + (rr&3)
//   af_kk[e] = d_{2kk+(e>>2)}[e&3]  -> zero cross-lane repack.
// f32 g (no unpacks; v_pk_mul_f32 tail). Proven flat global_load prefetch
// (r8/r11 idiom; NO SRSRC — r9/r12 failures share SRSRC), depth 4, straight-
// line while loads are in flight, vmcnt(15) counted waits (5 loads/step x 3
// outstanding), clamped refills, dummy masked step t=1024.
// Deadbeat normalizer (r10 lesson): measure after group step 0, apply
// EXACTLY ONCE at step 2; M += sln2 exact bookkeeping.
// ---------------------------------------------------------------------------
__global__ __launch_bounds__(256, 1) void crf_fused(
    const float* __restrict__ em,
    const float* __restrict__ gf,       // f32 exp(em), [B][T][K]
    const int* __restrict__ mask,
    const int* __restrict__ tags,
    const float* __restrict__ trans,
    const float* __restrict__ startT,
    const float* __restrict__ endT,
    float* __restrict__ logZ,
    float* __restrict__ gold,
    int nZ)
{
    __shared__ float wacc[4];
    __shared__ int   wcnt[4];

    if ((int)blockIdx.x >= nZ) {
        // ---------------- gold path score (one block per batch) ----------------
        const int b = (int)blockIdx.x - nZ;
        const int tid = threadIdx.x;
        const float* emb = em + (size_t)b * TT * KS;
        const int* tb = tags + (size_t)b * TT;
        const int* mb = mask + (size_t)b * TT;

        float acc = 0.f;
        int cnt = 0;
        for (int t = tid; t < TT; t += 256) {
            int tg = tb[t];
            int mv = mb[t];
            float mf = mv ? 1.f : 0.f;
            acc += emb[t * KS + tg] * mf;
            if (t >= 1) acc += trans[tb[t - 1] * KS + tg] * mf;
            cnt += mv ? 1 : 0;
        }
#pragma unroll
        for (int off = 32; off; off >>= 1) {
            acc += __shfl_xor(acc, off);
            cnt += __shfl_xor(cnt, off);
        }
        int wv = tid >> 6;
        if ((tid & 63) == 0) { wacc[wv] = acc; wcnt[wv] = cnt; }
        __syncthreads();
        if (tid == 0) {
            float a = wacc[0] + wacc[1] + wacc[2] + wacc[3];
            int   cc = wcnt[0] + wcnt[1] + wcnt[2] + wcnt[3];
            gold[b] = a + startT[tb[0]] + endT[tb[cc - 1]];
        }
        return;
    }

    // ---------------- logZ forward recursion (wave 0 only) ----------------
    if (threadIdx.x >= 64) return;
    __builtin_amdgcn_s_setprio(1);

    const int l = threadIdx.x;
    const int c = l & 15;
    const int h = l >> 4;
    const long long b = (long long)blockIdx.x * 16 + c;

    // constant transition fragments (A-operand), permuted columns sigma(m,c)
    const int sigc = 8 * (c >> 2) + (c & 3);
    bf16x8 E[4][2];
#pragma unroll
    for (int m = 0; m < 4; ++m) {
        const int col = 32 * (m >> 1) + 4 * (m & 1) + sigc;
#pragma unroll
        for (int kk = 0; kk < 2; ++kk) {
            union { unsigned short s[8]; bf16x8 v; } u;
#pragma unroll
            for (int e = 0; e < 8; ++e)
                u.s[e] = f2bf(__expf(trans[(32 * kk + 8 * h + e) * KS + col]));
            E[m][kk] = u.v;
        }
    }

    const long long embase = b * (long long)TT * KS;
    const unsigned long long gp =
        (unsigned long long)(const void*)((const char*)gf + embase * 4 + h * 32);
    const unsigned long long mp =
        (unsigned long long)(const void*)(mask + b * TT);

    // ---- state init at t=0: aw = bf16(exp(em0_j + start_j)) ----
    unsigned aw0, aw1, aw2, aw3, aw4, aw5, aw6, aw7;
    {
        const float* erow = em + embase;
        float w0[16];
#pragma unroll
        for (int kk = 0; kk < 2; ++kk)
#pragma unroll
            for (int e = 0; e < 8; ++e) {
                const int j = 32 * kk + 8 * h + e;
                w0[8 * kk + e] = __expf(erow[j] + startT[j]);
            }
        aw0 = cvtpk(w0[0], w0[1]);   aw1 = cvtpk(w0[2], w0[3]);
        aw2 = cvtpk(w0[4], w0[5]);   aw3 = cvtpk(w0[6], w0[7]);
        aw4 = cvtpk(w0[8], w0[9]);   aw5 = cvtpk(w0[10], w0[11]);
        aw6 = cvtpk(w0[12], w0[13]); aw7 = cvtpk(w0[14], w0[15]);
    }
    float M = 0.f;

    // ---- depth-4 prefetch slots (flat global_load, r8/r11-proven idiom) ----
    f32x4 gA[PFD], gB[PFD], gC[PFD], gD[PFD];
    int   mvp[PFD];
#pragma unroll
    for (int u = 0; u < PFD; ++u) {
        const unsigned long long a  = gp + (unsigned long long)(1 + u) * 256ull;
        const unsigned long long ma = mp + (unsigned long long)(1 + u) * 4ull;
        asm volatile("global_load_dwordx4 %0, %1, off" : "=&v"(gA[u]) : "v"(a));
        asm volatile("global_load_dwordx4 %0, %1, off offset:16" : "=&v"(gB[u]) : "v"(a));
        asm volatile("global_load_dwordx4 %0, %1, off offset:128" : "=&v"(gC[u]) : "v"(a));
        asm volatile("global_load_dwordx4 %0, %1, off offset:144" : "=&v"(gD[u]) : "v"(a));
        asm volatile("global_load_dword %0, %1, off" : "=&v"(mvp[u]) : "v"(ma));
    }

    // ---- deadbeat controller (absolute exponent re-center) ----
    unsigned kadd = 0;
    float    sln2 = 0.f;
#define CRF_CTRL() do {                                                        \
    const unsigned l0 = aw0 & 0xffffu, h0 = aw0 >> 16;                         \
    const unsigned l4 = aw4 & 0xffffu, h4 = aw4 >> 16;                         \
    unsigned um = l0 > h0 ? l0 : h0;                                           \
    um = um > l4 ? um : l4;  um = um > h4 ? um : h4;                           \
    unsigned sx = (unsigned)__shfl_xor((int)um, 16); um = um > sx ? um : sx;   \
    sx = (unsigned)__shfl_xor((int)um, 32);          um = um > sx ? um : sx;   \
    const unsigned k16 = (0x3F80u - (um & 0x7F80u)) & 0xffffu;                 \
    kadd = (k16 << 16) | k16;                                                  \
    sln2 = (float)((int)((um >> 7) & 0xffu) - 127) * 0.693147180559945f;       \
} while (0)

#define CRF_STEP(t, u, APPLY) do {                                             \
    union { unsigned uu[4]; bf16x8 v; } A0, A1;                                \
    A0.uu[0] = aw0; A0.uu[1] = aw1; A0.uu[2] = aw2; A0.uu[3] = aw3;            \
    A1.uu[0] = aw4; A1.uu[1] = aw5; A1.uu[2] = aw6; A1.uu[3] = aw7;            \
    const f32x4 z = {0.f, 0.f, 0.f, 0.f};                                      \
    f32x4 d0 = __builtin_amdgcn_mfma_f32_16x16x32_bf16(E[0][0], A0.v, z,0,0,0);\
    f32x4 d1 = __builtin_amdgcn_mfma_f32_16x16x32_bf16(E[1][0], A0.v, z,0,0,0);\
    f32x4 d2 = __builtin_amdgcn_mfma_f32_16x16x32_bf16(E[2][0], A0.v, z,0,0,0);\
    f32x4 d3 = __builtin_amdgcn_mfma_f32_16x16x32_bf16(E[3][0], A0.v, z,0,0,0);\
    d0 = __builtin_amdgcn_mfma_f32_16x16x32_bf16(E[0][1], A1.v, d0, 0,0,0);    \
    d1 = __builtin_amdgcn_mfma_f32_16x16x32_bf16(E[1][1], A1.v, d1, 0,0,0);    \
    d2 = __builtin_amdgcn_mfma_f32_16x16x32_bf16(E[2][1], A1.v, d2, 0,0,0);    \
    d3 = __builtin_amdgcn_mfma_f32_16x16x32_bf16(E[3][1], A1.v, d3, 0,0,0);    \
    asm volatile("s_waitcnt vmcnt(15)" ::: "memory");                          \
    __builtin_amdgcn_sched_barrier(0);                                         \
    const f32x4 v0 = gA[u], v1 = gB[u], v2 = gC[u], v3 = gD[u];                \
    const int mvv = ((t) <= TT - 1) ? mvp[u] : 0;                              \
    const f32x2 p0 = pkmul(lo2(d0), lo2(v0));                                  \
    const f32x2 p1 = pkmul(hi2(d0), hi2(v0));                                  \
    const f32x2 p2 = pkmul(lo2(d1), lo2(v1));                                  \
    const f32x2 p3 = pkmul(hi2(d1), hi2(v1));                                  \
    const f32x2 p4 = pkmul(lo2(d2), lo2(v2));                                  \
    const f32x2 p5 = pkmul(hi2(d2), hi2(v2));                                  \
    const f32x2 p6 = pkmul(lo2(d3), lo2(v3));                                  \
    const f32x2 p7 = pkmul(hi2(d3), hi2(v3));                                  \
    unsigned q0, q1, q2, q3, q4, q5, q6, q7;                                   \
    if (APPLY) {                                                               \
        q0 = pkadd(cvtpk(p0[0], p0[1]), kadd);                                 \
        q1 = pkadd(cvtpk(p1[0], p1[1]), kadd);                                 \
        q2 = pkadd(cvtpk(p2[0], p2[1]), kadd);                                 \
        q3 = pkadd(cvtpk(p3[0], p3[1]), kadd);                                 \
        q4 = pkadd(cvtpk(p4[0], p4[1]), kadd);                                 \
        q5 = pkadd(cvtpk(p5[0], p5[1]), kadd);                                 \
        q6 = pkadd(cvtpk(p6[0], p6[1]), kadd);                                 \
        q7 = pkadd(cvtpk(p7[0], p7[1]), kadd);                                 \
    } else {                                                                   \
        q0 = cvtpk(p0[0], p0[1]);  q1 = cvtpk(p1[0], p1[1]);                   \
        q2 = cvtpk(p2[0], p2[1]);  q3 = cvtpk(p3[0], p3[1]);                   \
        q4 = cvtpk(p4[0], p4[1]);  q5 = cvtpk(p5[0], p5[1]);                   \
        q6 = cvtpk(p6[0], p6[1]);  q7 = cvtpk(p7[0], p7[1]);                   \
    }                                                                          \
    aw0 = mvv ? q0 : aw0; aw1 = mvv ? q1 : aw1;                                \
    aw2 = mvv ? q2 : aw2; aw3 = mvv ? q3 : aw3;                                \
    aw4 = mvv ? q4 : aw4; aw5 = mvv ? q5 : aw5;                                \
    aw6 = mvv ? q6 : aw6; aw7 = mvv ? q7 : aw7;                                \
    if (APPLY) { M = mvv ? (M + sln2) : M; }                                   \
    {                                                                          \
        const int tn = ((t) + PFD <= TT - 1) ? ((t) + PFD) : (TT - 1);         \
        const unsigned long long a  = gp + (unsigned long long)tn * 256ull;    \
        const unsigned long long ma = mp + (unsigned long long)tn * 4ull;      \
        asm volatile("global_load_dwordx4 %0, %1, off" : "=&v"(gA[u]) : "v"(a)); \
        asm volatile("global_load_dwordx4 %0, %1, off offset:16" : "=&v"(gB[u]) : "v"(a)); \
        asm volatile("global_load_dwordx4 %0, %1, off offset:128" : "=&v"(gC[u]) : "v"(a)); \
        asm volatile("global_load_dwordx4 %0, %1, off offset:144" : "=&v"(gD[u]) : "v"(a)); \
        asm volatile("global_load_dword %0, %1, off" : "=&v"(mvp[u]) : "v"(ma)); \
    }                                                                          \
} while (0)

    // measure after group step 0; apply exactly once at step 2 (deadbeat)
    for (int t0 = 1; t0 < TT + 1; t0 += PFD) {
        CRF_STEP(t0 + 0, 0, 0);
        CRF_CTRL();
        CRF_STEP(t0 + 1, 1, 0);
        CRF_STEP(t0 + 2, 2, 1);
        CRF_STEP(t0 + 3, 3, 0);
    }
#undef CRF_STEP
#undef CRF_CTRL
    __builtin_amdgcn_s_setprio(0);

    // logZ_b = M + log(sum_j w_j * exp(end_j))
    float val = 0.f;
    {
        const unsigned a[8] = {aw0, aw1, aw2, aw3, aw4, aw5, aw6, aw7};
#pragma unroll
        for (int kk = 0; kk < 2; ++kk)
#pragma unroll
            for (int wi = 0; wi < 4; ++wi) {
                const int j0 = 32 * kk + 8 * h + 2 * wi;
                const unsigned wq = a[4 * kk + wi];
                val += bflo(wq) * __expf(endT[j0]);
                val += bfhi(wq) * __expf(endT[j0 + 1]);
            }
    }
    val += __shfl_xor(val, 16);
    val += __shfl_xor(val, 32);
    if (l < 16) logZ[(long long)blockIdx.x * 16 + l] = M + __logf(val);
}

// ---------------------------------------------------------------------------
// Fallback (workspace too small): r7-verified kernel, exp on the fly.
// ---------------------------------------------------------------------------
__global__ __launch_bounds__(64, 1) void crf_logZ_fb(
    const float* __restrict__ em, const int* __restrict__ mask,
    const float* __restrict__ trans, const float* __restrict__ startT,
    const float* __restrict__ endT, float* __restrict__ logZ)
{
    const int l = threadIdx.x;
    const int c = l & 15;
    const int h = l >> 4;
    const long long b = (long long)blockIdx.x * 16 + c;

    const int sigc = 8 * (c >> 2) + (c & 3);
    bf16x8 E[4][2];
#pragma unroll
    for (int m = 0; m < 4; ++m) {
        const int col = 32 * (m >> 1) + 4 * (m & 1) + sigc;
#pragma unroll
        for (int kk = 0; kk < 2; ++kk) {
            union { unsigned short s[8]; bf16x8 v; } u;
#pragma unroll
            for (int e = 0; e < 8; ++e)
                u.s[e] = f2bf(__expf(trans[(32 * kk + 8 * h + e) * KS + col]));
            E[m][kk] = u.v;
        }
    }
    const long long embase = b * (long long)TT * KS;
    const int* mrow = mask + b * TT;
    const float* erow = em + embase;

    unsigned aw[8];
    {
        float w0[16];
#pragma unroll
        for (int kk = 0; kk < 2; ++kk)
#pragma unroll
            for (int e = 0; e < 8; ++e) {
                const int j = 32 * kk + 8 * h + e;
                w0[8 * kk + e] = __expf(erow[j] + startT[j]);
            }
#pragma unroll
        for (int i = 0; i < 8; ++i) aw[i] = cvtpk(w0[2 * i], w0[2 * i + 1]);
    }
    float M = 0.f;

    for (int t = 1; t < TT; ++t) {
        union { unsigned uu[4]; bf16x8 v; } A0, A1;
#pragma unroll
        for (int i = 0; i < 4; ++i) { A0.uu[i] = aw[i]; A1.uu[i] = aw[4 + i]; }
        const f32x4 z = {0.f, 0.f, 0.f, 0.f};
        f32x4 d0 = __builtin_amdgcn_mfma_f32_16x16x32_bf16(E[0][0], A0.v, z,0,0,0);
        f32x4 d1 = __builtin_amdgcn_mfma_f32_16x16x32_bf16(E[1][0], A0.v, z,0,0,0);
        f32x4 d2 = __builtin_amdgcn_mfma_f32_16x16x32_bf16(E[2][0], A0.v, z,0,0,0);
        f32x4 d3 = __builtin_amdgcn_mfma_f32_16x16x32_bf16(E[3][0], A0.v, z,0,0,0);
        d0 = __builtin_amdgcn_mfma_f32_16x16x32_bf16(E[0][1], A1.v, d0, 0,0,0);
        d1 = __builtin_amdgcn_mfma_f32_16x16x32_bf16(E[1][1], A1.v, d1, 0,0,0);
        d2 = __builtin_amdgcn_mfma_f32_16x16x32_bf16(E[2][1], A1.v, d2, 0,0,0);
        d3 = __builtin_amdgcn_mfma_f32_16x16x32_bf16(E[3][1], A1.v, d3, 0,0,0);
        const float r0 = __shfl(d0.x, c);
        float gf[16];
#pragma unroll
        for (int kk = 0; kk < 2; ++kk)
#pragma unroll
            for (int e = 0; e < 8; ++e)
                gf[8 * kk + e] = __expf(erow[(long long)t * KS + 32 * kk + 8 * h + e]);
        const int sh = 127 - (int)((__float_as_uint(r0) >> 23) & 0xff);
        const unsigned k16 = (unsigned)(unsigned short)(sh * 128);
        const unsigned kadd = (k16 << 16) | k16;
        const int mv = mrow[t];
        const f32x4 dd[4] = {d0, d1, d2, d3};
#pragma unroll
        for (int i = 0; i < 8; ++i) {
            const f32x4 dv = dd[i >> 1];
            const float x = (i & 1) ? dv.z : dv.x;
            const float y = (i & 1) ? dv.w : dv.y;
            const unsigned q = pkadd(cvtpk(x * gf[2 * i], y * gf[2 * i + 1]), kadd);
            aw[i] = mv ? q : aw[i];
        }
        M = mv ? (M - (float)sh * 0.693147180559945f) : M;
    }

    float val = 0.f;
#pragma unroll
    for (int kk = 0; kk < 2; ++kk)
#pragma unroll
        for (int wi = 0; wi < 4; ++wi) {
            const int j0 = 32 * kk + 8 * h + 2 * wi;
            const unsigned wq = aw[4 * kk + wi];
            val += bflo(wq) * __expf(endT[j0]);
            val += bfhi(wq) * __expf(endT[j0 + 1]);
        }
    val += __shfl_xor(val, 16);
    val += __shfl_xor(val, 32);
    if (l < 16) logZ[(long long)blockIdx.x * 16 + l] = M + __logf(val);
}

// ---------------------------------------------------------------------------
// Standalone gold (fallback path only).
// ---------------------------------------------------------------------------
__global__ __launch_bounds__(256) void crf_gold_kernel(
    const float* __restrict__ em, const int* __restrict__ tags,
    const int* __restrict__ mask, const float* __restrict__ trans,
    const float* __restrict__ startT, const float* __restrict__ endT,
    float* __restrict__ gold, int T)
{
    const int b = blockIdx.x;
    const int tid = threadIdx.x;
    const float* emb = em + (size_t)b * T * KS;
    const int* tb = tags + (size_t)b * T;
    const int* mb = mask + (size_t)b * T;

    float acc = 0.f;
    int cnt = 0;
    for (int t = tid; t < T; t += 256) {
        int tg = tb[t];
        int mv = mb[t];
        float mf = mv ? 1.f : 0.f;
        acc += emb[t * KS + tg] * mf;
        if (t >= 1) acc += trans[tb[t - 1] * KS + tg] * mf;
        cnt += mv ? 1 : 0;
    }
#pragma unroll
    for (int off = 32; off; off >>= 1) {
        acc += __shfl_xor(acc, off);
        cnt += __shfl_xor(cnt, off);
    }
    __shared__ float wacc[4];
    __shared__ int   wcnt[4];
    int wv = tid >> 6;
    if ((tid & 63) == 0) { wacc[wv] = acc; wcnt[wv] = cnt; }
    __syncthreads();
    if (tid == 0) {
        float a = wacc[0] + wacc[1] + wacc[2] + wacc[3];
        int   cc = wcnt[0] + wcnt[1] + wcnt[2] + wcnt[3];
        gold[b] = a + startT[tb[0]] + endT[tb[cc - 1]];
    }
}

// ---------------------------------------------------------------------------
// mean(logZ - gold) -> scalar
// ---------------------------------------------------------------------------
__global__ __launch_bounds__(512) void crf_reduce_kernel(
    const float* __restrict__ logZ, const float* __restrict__ gold,
    float* __restrict__ out, int B)
{
    int tid = threadIdx.x;
    float v = 0.f;
    for (int i = tid; i < B; i += 512) v += logZ[i] - gold[i];
#pragma unroll
    for (int off = 32; off; off >>= 1) v += __shfl_xor(v, off);
    __shared__ float ws[8];
    int w = tid >> 6;
    if ((tid & 63) == 0) ws[w] = v;
    __syncthreads();
    if (tid == 0) {
        float s = 0.f;
#pragma unroll
        for (int k = 0; k < 8; ++k) s += ws[k];
        out[0] = s / (float)B;
    }
}

// ---------------------------------------------------------------------------
extern "C" void kernel_launch(void* const* d_in, const int* in_sizes, int n_in,
                              void* d_out, int out_size, void* d_ws, size_t ws_size,
                              hipStream_t stream)
{
    const float* emissions = (const float*)d_in[0];
    const int*   tags      = (const int*)d_in[1];
    const int*   mask      = (const int*)d_in[2];
    const float* trans     = (const float*)d_in[3];
    const float* startT    = (const float*)d_in[4];
    const float* endT      = (const float*)d_in[5];

    const int T = TT;
    const int B = in_sizes[1] / T;

    float* logZ = (float*)d_ws;
    float* gold = logZ + B;

    const size_t g32 = (size_t)B * T * KS * 4;

    if (ws_size >= 8192 + g32 && (B % 16) == 0) {
        float4* g = (float4*)((char*)d_ws + 8192);
        const int nZ = B / 16;
        crf_expem_f32<<<2048, 256, 0, stream>>>(
            emissions, g, (long long)B * T * KS / 4);
        crf_fused<<<nZ + B, 256, 0, stream>>>(
            emissions, (const float*)g, mask, tags, trans, startT, endT,
            logZ, gold, nZ);
    } else {
        crf_logZ_fb<<<B / 16, 64, 0, stream>>>(
            emissions, mask, trans, startT, endT, logZ);
        crf_gold_kernel<<<B, 256, 0, stream>>>(
            emissions, tags, mask, trans, startT, endT, gold, T);
    }
    crf_reduce_kernel<<<1, 512, 0, stream>>>(logZ, gold, (float*)d_out, B);
}